// Round 5
// baseline (147.916 us; speedup 1.0000x reference)
//
#include <hip/hip_runtime.h>
#include <cstdint>

#define NN 512
#define EE 64
#define HIDD 256
#define OUTD 32
#define L2E 1.4426950408889634f

typedef __bf16 bf16x8 __attribute__((ext_vector_type(8)));
typedef float f32x4 __attribute__((ext_vector_type(4)));
typedef float f32x2 __attribute__((ext_vector_type(2)));

// -------- device-global scratch (fully rewritten every call; deterministic) --------
__device__ float g_Wcomb[3*EE*EE];     // [q,k,v] combined: W?2 @ W?
__device__ float g_WhsT[HIDD*EE];      // W_hs transposed [k][e]
__device__ float g_M2T[EE*EE];         // M2T[c][e] (log2e*scale folded)
__device__ float g_cvec[EE];
__device__ uint4 g_Ag2[4096];          // bf16 A-fragments, gate-scaled; idx = w:3|mh:1|kh:2|lane:6
__device__ float g_biasI[256];         // [e][gate], gate-scaled
__device__ float g_embW[EE*4];         // per-e embed (a,b,bias,0)
__device__ float g_Wtot[OUTD*EE];      // W_o @ W_out @ Wv_comb
__device__ float g_btot[OUTD];

__device__ __forceinline__ float ex2(float x){ return __builtin_amdgcn_exp2f(x); }
__device__ __forceinline__ float rcp_(float x){ return __builtin_amdgcn_rcpf(x); }

// barrier that leaves vmcnt (global_load_lds) in flight
__device__ __forceinline__ void bar_lgkm() {
    asm volatile("s_waitcnt lgkmcnt(0)" ::: "memory");
    __builtin_amdgcn_s_barrier();
    __builtin_amdgcn_sched_barrier(0);
}
// barrier that drains everything (staged LDS becomes visible)
__device__ __forceinline__ void bar_full() {
    asm volatile("s_waitcnt vmcnt(0) lgkmcnt(0)" ::: "memory");
    __builtin_amdgcn_s_barrier();
    __builtin_amdgcn_sched_barrier(0);
}

// ---------------- prepW: weight packing ----------------
__global__ __launch_bounds__(256) void prepW(
    const float* __restrict__ W_ih, const float* __restrict__ b_ih,
    const float* __restrict__ W_hh, const float* __restrict__ b_hh,
    const float* __restrict__ Wq, const float* __restrict__ Wk, const float* __restrict__ Wv,
    const float* __restrict__ W_in, const float* __restrict__ W_hs,
    const float* __restrict__ W_s, const float* __restrict__ b_s,
    const float* __restrict__ W_v, const float* __restrict__ b_v)
{
    const int blk = blockIdx.x, tid = threadIdx.x;
    if (blk < 4) {
        // A-fragments: wave w (0..7) owns e in [8w,8w+8); e = 8w + 2*qq + mh; m = 4*qq+gate
#pragma unroll
        for (int ii = 0; ii < 4; ++ii) {
            int idx = blk*1024 + ii*256 + tid;
            int w = idx >> 9, mh = (idx >> 8) & 1, kh = (idx >> 6) & 3, lane = idx & 63;
            int m = lane & 15, qq = m >> 2, gate = m & 3;
            int e = 8*w + 2*qq + mh;
            int o = gate*64 + e;
            int kb = kh*32 + (lane >> 4)*8;
            float sc = (gate == 2) ? (-2.f*L2E) : (-L2E);
            bf16x8 vv;
#pragma unroll
            for (int j = 0; j < 8; ++j) {
                int k = kb + j;
                float raw = (k < 64) ? W_ih[o*64 + k] : W_hh[o*64 + (k - 64)];
                vv[j] = (__bf16)(sc * raw);
            }
            g_Ag2[idx] = __builtin_bit_cast(uint4, vv);
        }
    } else if (blk == 4) {
        {
            int e = tid >> 2, gate = tid & 3, o = gate*64 + e;
            float sc = (gate == 2) ? (-2.f*L2E) : (-L2E);
            g_biasI[tid] = sc * (b_ih[o] + b_hh[o]);
        }
        if (tid < 64) {
            int e = tid;
            if (e < 32) {
                g_embW[e*4+0] = W_s[e*2]; g_embW[e*4+1] = W_s[e*2+1]; g_embW[e*4+2] = b_s[e];
            } else {
                g_embW[e*4+0] = 4.f*W_v[(e-32)*2]; g_embW[e*4+1] = 4.f*W_v[(e-32)*2+1]; g_embW[e*4+2] = b_v[e-32];
            }
            g_embW[e*4+3] = 0.f;
        }
        for (int idx = tid; idx < HIDD*EE; idx += 256) {
            int k = idx >> 6, e = idx & 63;
            g_WhsT[idx] = W_hs[e*HIDD + k];
        }
    } else {
        int t = blk - 5;
        const float* W2 = W_in + t*4096;
        const float* W1 = (t == 0) ? Wq : ((t == 1) ? Wk : Wv);
        for (int idx = tid; idx < 4096; idx += 256) {
            int a = idx >> 6, c = idx & 63;
            float s = 0.f;
            for (int m = 0; m < 64; ++m) s = fmaf(W2[a*64 + m], W1[m*64 + c], s);
            g_Wcomb[t*4096 + idx] = s;
        }
    }
}

// ---------------- prepW2: M2T/cvec (blk0) + fused output proj (blk1) --------
__global__ __launch_bounds__(256) void prepW2(
    const float* __restrict__ b_in, const float* __restrict__ W_out,
    const float* __restrict__ b_out, const float* __restrict__ W_o,
    const float* __restrict__ b_o)
{
    const int tid = threadIdx.x;
    if (blockIdx.x == 0) {
        const float* Wqc = g_Wcomb;
        const float* Wkc = g_Wcomb + 4096;
        for (int idx = tid; idx < 4096; idx += 256) {
            int c = idx >> 6, e = idx & 63;
            float s = 0.f;
            for (int a = 0; a < 64; ++a) s = fmaf(Wkc[a*64 + e], Wqc[a*64 + c], s);
            g_M2T[idx] = s * (L2E * 0.125f);
        }
        if (tid < 64) {
            float s = 0.f;
            for (int a = 0; a < 64; ++a) s = fmaf(g_Wcomb[4096 + a*64 + tid], b_in[a], s);
            g_cvec[tid] = s * (L2E * 0.125f);
        }
    } else {
        __shared__ float Wtmp[4096];
        __shared__ float bb[64];
        for (int idx = tid; idx < 4096; idx += 256) {
            int i = idx >> 6, jj = idx & 63;
            float s = 0.f;
            for (int k = 0; k < 64; ++k) s = fmaf(W_out[i*64 + k], g_Wcomb[2*4096 + k*64 + jj], s);
            Wtmp[idx] = s;
        }
        if (tid < 64) {
            float s = 0.f;
            for (int k = 0; k < 64; ++k) s = fmaf(W_out[tid*64 + k], b_in[128 + k], s);
            bb[tid] = s + b_out[tid];
        }
        __syncthreads();
        for (int idx = tid; idx < OUTD*64; idx += 256) {
            int o = idx >> 6, jj = idx & 63;
            float s = 0.f;
            for (int i = 0; i < 64; ++i) s = fmaf(W_o[o*64 + i], Wtmp[i*64 + jj], s);
            g_Wtot[idx] = s;
        }
        if (tid < OUTD) {
            float s = 0.f;
            for (int i = 0; i < 64; ++i) s = fmaf(W_o[tid*64 + i], bb[i], s);
            g_btot[tid] = s + b_o[tid];
        }
    }
}

// ---------------- row kernel: 512 blocks x 512 threads (8 waves), full row --
__global__ __launch_bounds__(512, 4) void row_kernel(
    const float* __restrict__ hidden, const float* __restrict__ b_hs,
    const float* __restrict__ obs1, const float* __restrict__ obs2,
    const float* __restrict__ h0, const float* __restrict__ c0,
    float* __restrict__ out)
{
    __shared__ __align__(16) float Hs[2][64*64];          // 2 x 16KB, swizzled rows (256B)
    __shared__ __align__(16) unsigned short Xe[64*64];    // 8KB bf16, swizzled rows (128B)
    __shared__ float spart[8][64];
    __shared__ float embw4[64][4];                        // XOR-swizzled slots
    __shared__ float hid[HIDD];
    __shared__ float part[8][64];
    __shared__ float hsL[64], qkL[64];
    __shared__ float ctxE[64];

    const int b = blockIdx.x, tid = threadIdx.x;
    const int w = tid >> 6, l = tid & 63;
    const int q = l >> 4, r = l & 15;
    const int ebase0 = 8*w + 2*q;                          // thread's e-pair base (mh 0,1)
    const size_t rowbase = (size_t)b * NN * EE;
    const float* h0r = h0 + rowbase;
    const float* c0r = c0 + rowbase;

    const float ob2x = obs2[b*2], ob2y = obs2[b*2+1];
    const float ob1x = obs1[b*2], ob1y = obs1[b*2+1];
    const float velbx = ob2x - ob1x, velby = ob2y - ob1y;

    // ---- staging helper: H tile (16KB) via global_load_lds, pre-swizzled src ----
    auto stageH = [&](const float* gsrc, int buf) {
#pragma unroll
        for (int i = 0; i < 2; ++i) {
            const int row = (tid >> 4) + i*32;
            const int cb  = (tid & 15) * 16;
            const char* g = (const char*)gsrc + row*256 + (cb ^ ((row & 7) << 4));
            char* lp = (char*)&Hs[buf][0] + row*256 + cb;
            __builtin_amdgcn_global_load_lds(
                (const __attribute__((address_space(1))) void*)g,
                (__attribute__((address_space(3))) void*)lp, 16, 0, 0);
        }
    };
    // ---- distributed embed: thread computes 8 e's of one row; swizzled write ----
    auto embedW = [&](int jb) {
        const int p = tid >> 3, oct = tid & 7;
        const int j = jb + p;
        const float2 o2 = *(const float2*)(obs2 + 2*j);
        const float2 o1 = *(const float2*)(obs1 + 2*j);
        const float u0s = o2.x - ob2x, u1s = o2.y - ob2y;
        const float u0v = (o2.x - o1.x) - velbx, u1v = (o2.y - o1.y) - velby;
        const bool sph = (oct < 4);
        const float u0 = sph ? u0s : u0v, u1 = sph ? u1s : u1v;
        bf16x8 pk;
#pragma unroll
        for (int i2 = 0; i2 < 8; ++i2) {
            const float* wv = &embw4[oct*8 + (i2 ^ oct)][0];   // swizzled slot -> e = oct*8+i2
            float v = fmaxf(fmaf(wv[0], u0, fmaf(wv[1], u1, wv[2])), 0.f);
            pk[i2] = (__bf16)v;
        }
        *(bf16x8*)((char*)Xe + p*128 + ((oct*16) ^ ((p & 7) << 4))) = pk;
    };

    // ---- prologue: A-frags, stage tile0, embw/hid fill, hs/qk compute ----
    uint4 Afr[2][4];
#pragma unroll
    for (int mh = 0; mh < 2; ++mh)
#pragma unroll
        for (int kh = 0; kh < 4; ++kh)
            Afr[mh][kh] = g_Ag2[w*512 + mh*256 + kh*64 + l];

    stageH(h0r, 0);

    if (tid < 64) {
        int es = (tid & ~7) | ((tid ^ (tid >> 3)) & 7);    // slot s holds e = s&~7 | ((s^s>>3)&7)
        *(float4*)&embw4[tid][0] = *(const float4*)(g_embW + es*4);
    }
    if (tid < 256) hid[tid] = hidden[b*HIDD + tid];
    __syncthreads();
    {   // hs = WhsT^T @ hid + b_hs
        float s = 0.f;
#pragma unroll 8
        for (int k2 = 0; k2 < 32; ++k2) {
            int kk = w*32 + k2;
            s = fmaf(g_WhsT[kk*64 + l], hid[kk], s);
        }
        part[w][l] = s;
    }
    __syncthreads();
    if (tid < 64) {
        float v = b_hs[tid];
#pragma unroll
        for (int i = 0; i < 8; ++i) v += part[i][tid];
        hsL[tid] = v;
    }
    __syncthreads();
    {   // qk = M2T^T @ hs + cvec
        float s = 0.f;
#pragma unroll
        for (int k2 = 0; k2 < 8; ++k2) {
            int kk = w*8 + k2;
            s = fmaf(g_M2T[kk*64 + l], hsL[kk], s);
        }
        part[w][l] = s;
    }
    __syncthreads();
    if (tid < 64) {
        float v = g_cvec[tid];
#pragma unroll
        for (int i = 0; i < 8; ++i) v += part[i][tid];
        qkL[tid] = v;
    }
    embedW(0);
    __syncthreads();                       // full drain: tile0 staged + qkL/Xe visible

    const f32x2 qkr = *(const f32x2*)&qkL[ebase0];
    const f32x2 hsd = *(const f32x2*)&hsL[ebase0];
    f32x4 biasv[2];
#pragma unroll
    for (int mh = 0; mh < 2; ++mh) {
        float4 t4 = *(const float4*)(g_biasI + (ebase0 + mh)*4);
        biasv[mh][0]=t4.x; biasv[mh][1]=t4.y; biasv[mh][2]=t4.z; biasv[mh][3]=t4.w;
    }

    float m_run = -__builtin_inff(), l_run = 0.f;
    float ctxa[2] = {0.f, 0.f};

    for (int t = 0; t < 8; ++t) {
        const int jbase = t*64;
        const int cur = t & 1;

        // ---- issue c0 loads for this tile (consumed after MFMA) ----
        f32x2 cpre[4];
#pragma unroll
        for (int nh = 0; nh < 4; ++nh)
            cpre[nh] = *(const f32x2*)(c0r + (size_t)(jbase + 16*nh + r)*EE + ebase0);
        // ---- issue next H tile stage (lands by end-of-tile vmcnt(0)) ----
        if (t < 7) stageH(h0r + (size_t)(jbase + 64)*EE, cur ^ 1);

        // ---- gates MFMA: kh 0,1 from Xe; kh 2,3 from Hs[cur] ----
        f32x4 acc[2][4];
#pragma unroll
        for (int mh = 0; mh < 2; ++mh)
#pragma unroll
            for (int nh = 0; nh < 4; ++nh) acc[mh][nh] = biasv[mh];
#pragma unroll
        for (int kh = 0; kh < 4; ++kh) {
            const bf16x8 Af0 = __builtin_bit_cast(bf16x8, Afr[0][kh]);
            const bf16x8 Af1 = __builtin_bit_cast(bf16x8, Afr[1][kh]);
#pragma unroll
            for (int nh = 0; nh < 4; ++nh) {
                const int p = 16*nh + r;
                const int sw = (p & 7) << 4;
                bf16x8 Bf;
                if (kh < 2) {
                    Bf = *(const bf16x8*)((const char*)Xe + p*128 + ((kh*64 + q*16) ^ sw));
                } else {
                    const char* hb = (const char*)&Hs[cur][0] + p*256;
                    const int cbb = (kh - 2)*128 + q*32;
                    f32x4 f0 = *(const f32x4*)(hb + (cbb ^ sw));
                    f32x4 f1 = *(const f32x4*)(hb + ((cbb + 16) ^ sw));
                    Bf[0]=(__bf16)f0[0]; Bf[1]=(__bf16)f0[1]; Bf[2]=(__bf16)f0[2]; Bf[3]=(__bf16)f0[3];
                    Bf[4]=(__bf16)f1[0]; Bf[5]=(__bf16)f1[1]; Bf[6]=(__bf16)f1[2]; Bf[7]=(__bf16)f1[3];
                }
                acc[0][nh] = __builtin_amdgcn_mfma_f32_16x16x32_bf16(Af0, Bf, acc[0][nh], 0, 0, 0);
                acc[1][nh] = __builtin_amdgcn_mfma_f32_16x16x32_bf16(Af1, Bf, acc[1][nh], 0, 0, 0);
            }
        }

        // ---- LSTM elementwise (base-2) + score partials ----
        float Eev[2][4];
        float sp[4] = {0.f, 0.f, 0.f, 0.f};
#pragma unroll
        for (int nh = 0; nh < 4; ++nh) {
#pragma unroll
            for (int mh = 0; mh < 2; ++mh) {
                f32x4 g4 = acc[mh][nh];
                float si = rcp_(1.f + ex2(g4[0]));
                float sf = rcp_(1.f + ex2(g4[1]));
                float so = rcp_(1.f + ex2(g4[3]));
                float tt = ex2(-__builtin_fabsf(g4[2]));
                float tg = __builtin_copysignf((1.f - tt) * rcp_(1.f + tt), -g4[2]);
                float cn = fmaf(sf, cpre[nh][mh], si * tg);
                float t2 = ex2(-__builtin_fabsf(cn) * (2.f * L2E));
                float tc = __builtin_copysignf((1.f - t2) * rcp_(1.f + t2), cn);
                float h = so * tc;
                h = (16*nh + r == b - jbase) ? hsd[mh] : h;
                Eev[mh][nh] = h;
                sp[nh] = fmaf(qkr[mh], h, sp[nh]);
            }
        }
#pragma unroll
        for (int nh = 0; nh < 4; ++nh) {
            float v = sp[nh];
            v += __shfl_xor(v, 16, 64);
            v += __shfl_xor(v, 32, 64);
            if (q == 0) spart[w][16*nh + r] = v;
        }
        bar_lgkm();                      // spart visible; H-stage stays in flight

        // ---- online softmax (base-2) + ctx accumulation ----
        {
            float s_p = spart[0][l];
#pragma unroll
            for (int i = 1; i < 8; ++i) s_p += spart[i][l];
            float tm = s_p;
#pragma unroll
            for (int off = 1; off < 64; off <<= 1) tm = fmaxf(tm, __shfl_xor(tm, off, 64));
            float m_new = fmaxf(m_run, tm);
            float corr = ex2(m_run - m_new);
            float wp = ex2(s_p - m_new);
            l_run = fmaf(l_run, corr, wp);
            m_run = m_new;
            float wn[4];
#pragma unroll
            for (int nh = 0; nh < 4; ++nh) wn[nh] = __shfl(wp, 16*nh + r, 64);
#pragma unroll
            for (int mh = 0; mh < 2; ++mh) {
                float a = ctxa[mh] * corr;
#pragma unroll
                for (int nh = 0; nh < 4; ++nh) a = fmaf(wn[nh], Eev[mh][nh], a);
                ctxa[mh] = a;
            }
        }
        // ---- embed for next tile (after all Xe reads of tile t) ----
        if (t < 7) embedW(jbase + 64);
        bar_full();                      // next H tile + Xe visible
    }

    // ---- epilogue: normalize, reduce, fused output projection ----
    float l_tot = l_run;
#pragma unroll
    for (int off = 1; off < 64; off <<= 1) l_tot += __shfl_xor(l_tot, off, 64);
    const float inv = rcp_(l_tot);
#pragma unroll
    for (int mh = 0; mh < 2; ++mh) {
        float v = ctxa[mh];
        v += __shfl_xor(v, 1, 64);
        v += __shfl_xor(v, 2, 64);
        v += __shfl_xor(v, 4, 64);
        v += __shfl_xor(v, 8, 64);
        if (r == 0) ctxE[ebase0 + mh] = v * inv;
    }
    __syncthreads();
    if (tid < OUTD) {
        float s = g_btot[tid];
        const float* wr2 = g_Wtot + tid*64;
        for (int k = 0; k < 64; ++k) s = fmaf(wr2[k], ctxE[k], s);
        out[b*OUTD + tid] = s;
    }
}

extern "C" void kernel_launch(void* const* d_in, const int* in_sizes, int n_in,
                              void* d_out, int out_size, void* d_ws, size_t ws_size,
                              hipStream_t stream) {
    const float* hidden = (const float*)d_in[0];
    const float* obs1   = (const float*)d_in[1];
    const float* obs2   = (const float*)d_in[2];
    const float* h0     = (const float*)d_in[3];
    const float* c0     = (const float*)d_in[4];
    const float* W_s    = (const float*)d_in[5];
    const float* b_s    = (const float*)d_in[6];
    const float* W_v    = (const float*)d_in[7];
    const float* b_v    = (const float*)d_in[8];
    const float* W_hs   = (const float*)d_in[9];
    const float* b_hs   = (const float*)d_in[10];
    const float* W_ih   = (const float*)d_in[11];
    const float* b_ih   = (const float*)d_in[12];
    const float* W_hh   = (const float*)d_in[13];
    const float* b_hh   = (const float*)d_in[14];
    const float* Wq     = (const float*)d_in[15];
    const float* Wk     = (const float*)d_in[16];
    const float* Wv     = (const float*)d_in[17];
    const float* W_in   = (const float*)d_in[18];
    const float* b_in   = (const float*)d_in[19];
    const float* W_out  = (const float*)d_in[20];
    const float* b_out  = (const float*)d_in[21];
    const float* W_o    = (const float*)d_in[22];
    const float* b_o    = (const float*)d_in[23];

    prepW<<<dim3(8), dim3(256), 0, stream>>>(
        W_ih, b_ih, W_hh, b_hh, Wq, Wk, Wv, W_in, W_hs, W_s, b_s, W_v, b_v);
    prepW2<<<dim3(2), dim3(256), 0, stream>>>(b_in, W_out, b_out, W_o, b_o);
    row_kernel<<<dim3(NN), dim3(512), 0, stream>>>(
        hidden, b_hs, obs1, obs2, h0, c0, (float*)d_out);
}

// Round 6
// 111.713 us; speedup vs baseline: 1.3241x; 1.3241x over previous
//
#include <hip/hip_runtime.h>
#include <cstdint>

#define NN 512
#define EE 64
#define HIDD 256
#define OUTD 32
#define HALF 256
#define TILE 32
#define NT 8
#define L2E 1.4426950408889634f

typedef __bf16 bf16x8 __attribute__((ext_vector_type(8)));
typedef __bf16 bf16x4 __attribute__((ext_vector_type(4)));
typedef float f32x4 __attribute__((ext_vector_type(4)));
typedef float f32x2 __attribute__((ext_vector_type(2)));

// -------- device-global scratch (fully rewritten every call; deterministic) --------
__device__ float g_Wcomb[3*EE*EE];     // [q,k,v] combined: W?2 @ W?
__device__ float g_WhsT[HIDD*EE];      // W_hs transposed [k][e]
__device__ float g_M2T[EE*EE];         // M2T[c][e] (log2e*scale folded)
__device__ float g_cvec[EE];
__device__ uint4 g_Ag2[4096];          // bf16 A-fragments, gate-scaled; idx = w:3|mh:1|kh:2|lane:6
__device__ float g_biasI[256];         // [e][gate], gate-scaled
__device__ float g_embW[EE*4];         // per-e embed (a,b,bias,0)
__device__ float g_Wtot[OUTD*EE];      // W_o @ W_out @ Wv_comb
__device__ float g_btot[OUTD];
__device__ float g_part[2*NN][68];     // per (b,half): ctx_u[64], m, l

__device__ __forceinline__ float ex2(float x){ return __builtin_amdgcn_exp2f(x); }
__device__ __forceinline__ float rcp_(float x){ return __builtin_amdgcn_rcpf(x); }

// ---------------- prepW: weight packing ----------------
__global__ __launch_bounds__(256) void prepW(
    const float* __restrict__ W_ih, const float* __restrict__ b_ih,
    const float* __restrict__ W_hh, const float* __restrict__ b_hh,
    const float* __restrict__ Wq, const float* __restrict__ Wk, const float* __restrict__ Wv,
    const float* __restrict__ W_in, const float* __restrict__ W_hs,
    const float* __restrict__ W_s, const float* __restrict__ b_s,
    const float* __restrict__ W_v, const float* __restrict__ b_v)
{
    const int blk = blockIdx.x, tid = threadIdx.x;
    if (blk < 4) {
        // A-fragments: wave w (0..7) owns e in [8w,8w+8); e = 8w + 2*qq + mh; m = 4*qq+gate
#pragma unroll
        for (int ii = 0; ii < 4; ++ii) {
            int idx = blk*1024 + ii*256 + tid;
            int w = idx >> 9, mh = (idx >> 8) & 1, kh = (idx >> 6) & 3, lane = idx & 63;
            int m = lane & 15, qq = m >> 2, gate = m & 3;
            int e = 8*w + 2*qq + mh;
            int o = gate*64 + e;
            int kb = kh*32 + (lane >> 4)*8;
            float sc = (gate == 2) ? (-2.f*L2E) : (-L2E);
            bf16x8 vv;
#pragma unroll
            for (int j = 0; j < 8; ++j) {
                int k = kb + j;
                float raw = (k < 64) ? W_ih[o*64 + k] : W_hh[o*64 + (k - 64)];
                vv[j] = (__bf16)(sc * raw);
            }
            g_Ag2[idx] = __builtin_bit_cast(uint4, vv);
        }
    } else if (blk == 4) {
        __shared__ float T[64][65];
        {
            int e = tid >> 2, gate = tid & 3, o = gate*64 + e;
            float sc = (gate == 2) ? (-2.f*L2E) : (-L2E);
            g_biasI[tid] = sc * (b_ih[o] + b_hh[o]);
        }
        if (tid < 64) {
            int e = tid;
            if (e < 32) {
                g_embW[e*4+0] = W_s[e*2]; g_embW[e*4+1] = W_s[e*2+1]; g_embW[e*4+2] = b_s[e];
            } else {
                g_embW[e*4+0] = 4.f*W_v[(e-32)*2]; g_embW[e*4+1] = 4.f*W_v[(e-32)*2+1]; g_embW[e*4+2] = b_v[e-32];
            }
            g_embW[e*4+3] = 0.f;
        }
        // coalesced LDS-tiled transpose of W_hs [64][256] -> g_WhsT [256][64]
        for (int kt = 0; kt < 4; ++kt) {
            __syncthreads();
#pragma unroll
            for (int i = 0; i < 16; ++i) {
                int row = i*4 + (tid >> 6);
                int col = tid & 63;
                T[col][row] = W_hs[row*256 + kt*64 + col];
            }
            __syncthreads();
#pragma unroll
            for (int i = 0; i < 16; ++i) {
                int krow = i*4 + (tid >> 6);
                int e = tid & 63;
                g_WhsT[(kt*64 + krow)*64 + e] = T[krow][e];
            }
        }
    } else {
        int t = blk - 5;
        const float* W2 = W_in + t*4096;
        const float* W1 = (t == 0) ? Wq : ((t == 1) ? Wk : Wv);
        for (int idx = tid; idx < 4096; idx += 256) {
            int a = idx >> 6, c = idx & 63;
            float s = 0.f;
            for (int m = 0; m < 64; ++m) s = fmaf(W2[a*64 + m], W1[m*64 + c], s);
            g_Wcomb[t*4096 + idx] = s;
        }
    }
}

// ---------------- prepW2: M2T/cvec (blk0) + fused output proj (blk1) --------
__global__ __launch_bounds__(256) void prepW2(
    const float* __restrict__ b_in, const float* __restrict__ W_out,
    const float* __restrict__ b_out, const float* __restrict__ W_o,
    const float* __restrict__ b_o)
{
    const int tid = threadIdx.x;
    if (blockIdx.x == 0) {
        const float* Wqc = g_Wcomb;
        const float* Wkc = g_Wcomb + 4096;
        for (int idx = tid; idx < 4096; idx += 256) {
            int c = idx >> 6, e = idx & 63;
            float s = 0.f;
            for (int a = 0; a < 64; ++a) s = fmaf(Wkc[a*64 + e], Wqc[a*64 + c], s);
            g_M2T[idx] = s * (L2E * 0.125f);
        }
        if (tid < 64) {
            float s = 0.f;
            for (int a = 0; a < 64; ++a) s = fmaf(g_Wcomb[4096 + a*64 + tid], b_in[a], s);
            g_cvec[tid] = s * (L2E * 0.125f);
        }
    } else {
        __shared__ float Wtmp[4096];
        __shared__ float bb[64];
        for (int idx = tid; idx < 4096; idx += 256) {
            int i = idx >> 6, jj = idx & 63;
            float s = 0.f;
            for (int k = 0; k < 64; ++k) s = fmaf(W_out[i*64 + k], g_Wcomb[2*4096 + k*64 + jj], s);
            Wtmp[idx] = s;
        }
        if (tid < 64) {
            float s = 0.f;
            for (int k = 0; k < 64; ++k) s = fmaf(W_out[tid*64 + k], b_in[128 + k], s);
            bb[tid] = s + b_out[tid];
        }
        __syncthreads();
        for (int idx = tid; idx < OUTD*64; idx += 256) {
            int o = idx >> 6, jj = idx & 63;
            float s = 0.f;
            for (int i = 0; i < 64; ++i) s = fmaf(W_o[o*64 + i], Wtmp[i*64 + jj], s);
            g_Wtot[idx] = s;
        }
        if (tid < OUTD) {
            float s = 0.f;
            for (int i = 0; i < 64; ++i) s = fmaf(W_o[tid*64 + i], bb[i], s);
            g_btot[tid] = s + b_o[tid];
        }
    }
}

// ---------------- row kernel: 1024 blocks x 512 thr, (row b, half), 8 tiles of 32 ----
__global__ __launch_bounds__(512, 4) void row_kernel(
    const float* __restrict__ hidden, const float* __restrict__ b_hs,
    const float* __restrict__ obs1, const float* __restrict__ obs2,
    const float* __restrict__ h0, const float* __restrict__ c0)
{
    __shared__ __align__(16) float Hs[2][TILE*EE];        // 2 x 8KB, swizzled 256B rows
    __shared__ __align__(16) float Cs[2][TILE*EE];        // 2 x 8KB
    __shared__ __align__(16) unsigned short Xe[TILE*EE];  // 4KB bf16, swizzled 128B rows
    __shared__ float2 obs1L[HALF], obs2L[HALF];           // 4KB
    __shared__ float hid[HIDD];
    __shared__ float part[8][64];
    __shared__ float hsL[64], qkL[64];
    __shared__ float spart[8][TILE];

    const int bh = blockIdx.x;
    const int b = bh >> 1, half = bh & 1;
    const int tid = threadIdx.x;
    const int w = tid >> 6, l = tid & 63;
    const int q = l >> 4, r = l & 15;
    const int ebase0 = 8*w + 2*q;
    const size_t rowbase = (size_t)b * NN * EE;
    const float* hp_half = h0 + rowbase + (size_t)half*HALF*EE;
    const float* cp_half = c0 + rowbase + (size_t)half*HALF*EE;

    // ---- register hoists (global loads, prologue only) ----
    uint4 Afr[2][4];
#pragma unroll
    for (int mh = 0; mh < 2; ++mh)
#pragma unroll
        for (int kh = 0; kh < 4; ++kh)
            Afr[mh][kh] = g_Ag2[w*512 + mh*256 + kh*64 + l];
    f32x4 biasv[2];
#pragma unroll
    for (int mh = 0; mh < 2; ++mh) {
        float4 t4 = *(const float4*)(g_biasI + (ebase0 + mh)*4);
        biasv[mh][0]=t4.x; biasv[mh][1]=t4.y; biasv[mh][2]=t4.z; biasv[mh][3]=t4.w;
    }
    // per-thread embed weights: 4 e's = (tid&15)*4 .. +4  (tile-invariant)
    float eA[4], eB[4], eC[4];
    {
        const int e0 = (tid & 15)*4;
#pragma unroll
        for (int i = 0; i < 4; ++i) {
            eA[i] = g_embW[(e0+i)*4+0]; eB[i] = g_embW[(e0+i)*4+1]; eC[i] = g_embW[(e0+i)*4+2];
        }
    }
    const float ob2x = obs2[b*2], ob2y = obs2[b*2+1];
    const float ob1x = obs1[b*2], ob1y = obs1[b*2+1];
    const float velbx = ob2x - ob1x, velby = ob2y - ob1y;

    // ---- staging: 1 global_load_lds per thread per buffer (16B), pre-swizzled src ----
    auto stageT = [&](const float* gsrc, float* lbuf) {
        const int row = tid >> 4;
        const int cb  = (tid & 15) * 16;
        const char* g = (const char*)gsrc + row*256 + (cb ^ ((row & 15) << 4));
        char* lp = (char*)lbuf + tid*16;
        __builtin_amdgcn_global_load_lds(
            (const __attribute__((address_space(1))) void*)g,
            (__attribute__((address_space(3))) void*)lp, 16, 0, 0);
    };
    // ---- embed tile (32 pairs x 64 e): thread = (p = tid>>4, 4 e's), from LDS obs ----
    auto embedW = [&](int tb) {
        const int p = tid >> 4;
        const float2 o2 = obs2L[tb + p];
        const float2 o1 = obs1L[tb + p];
        const float u0s = o2.x - ob2x, u1s = o2.y - ob2y;
        const float u0v = (o2.x - o1.x) - velbx, u1v = (o2.y - o1.y) - velby;
        const bool sph = ((tid & 15) < 8);
        const float u0 = sph ? u0s : u0v, u1 = sph ? u1s : u1v;
        bf16x4 pk;
#pragma unroll
        for (int i = 0; i < 4; ++i)
            pk[i] = (__bf16)fmaxf(fmaf(eA[i], u0, fmaf(eB[i], u1, eC[i])), 0.f);
        *(bf16x4*)((char*)Xe + p*128 + (((tid & 15)*8) ^ ((p & 7) << 4))) = pk;
    };

    // ---- prologue: stage tile0; obs/hid -> LDS; hs/qk compute; embed(0) ----
    stageT(hp_half, Hs[0]);
    stageT(cp_half, Cs[0]);
    if (tid < HALF) {
        obs2L[tid] = ((const float2*)obs2)[half*HALF + tid];
        obs1L[tid] = ((const float2*)obs1)[half*HALF + tid];
    }
    if (tid < HIDD) hid[tid] = hidden[b*HIDD + tid];
    __syncthreads();
    {   // hs = W_hs @ hidden + b_hs   (thread (w,l): k-chunk 32, e = l)
        float s = 0.f;
#pragma unroll 8
        for (int k2 = 0; k2 < 32; ++k2) {
            int kk = w*32 + k2;
            s = fmaf(g_WhsT[kk*64 + l], hid[kk], s);
        }
        part[w][l] = s;
    }
    __syncthreads();
    if (tid < 64) {
        float v = b_hs[tid];
#pragma unroll
        for (int i = 0; i < 8; ++i) v += part[i][tid];
        hsL[tid] = v;
    }
    __syncthreads();
    {   // qk = M2T^T @ hs + cvec
        float s = 0.f;
#pragma unroll
        for (int k2 = 0; k2 < 8; ++k2) {
            int kk = w*8 + k2;
            s = fmaf(g_M2T[kk*64 + l], hsL[kk], s);
        }
        part[w][l] = s;
    }
    __syncthreads();
    if (tid < 64) {
        float v = g_cvec[tid];
#pragma unroll
        for (int i = 0; i < 8; ++i) v += part[i][tid];
        qkL[tid] = v;
    }
    __syncthreads();
    embedW(0);
    const f32x2 qkr = *(const f32x2*)&qkL[ebase0];
    const f32x2 hsd = *(const f32x2*)&hsL[ebase0];
    asm volatile("s_waitcnt vmcnt(0) lgkmcnt(0)" ::: "memory");
    __builtin_amdgcn_s_barrier();
    __builtin_amdgcn_sched_barrier(0);

    float m_run = -__builtin_inff(), l_run = 0.f;
    float ctxa[2] = {0.f, 0.f};

    for (int t = 0; t < NT; ++t) {
        const int cur = t & 1;
        const int base = half*HALF + t*TILE;

        // ---- phase A: MFMA + cpre (LDS only) ----
        f32x4 acc[2][2];
#pragma unroll
        for (int mh = 0; mh < 2; ++mh)
#pragma unroll
            for (int nh = 0; nh < 2; ++nh) acc[mh][nh] = biasv[mh];
#pragma unroll
        for (int kh = 0; kh < 4; ++kh) {
            const bf16x8 Af0 = __builtin_bit_cast(bf16x8, Afr[0][kh]);
            const bf16x8 Af1 = __builtin_bit_cast(bf16x8, Afr[1][kh]);
#pragma unroll
            for (int nh = 0; nh < 2; ++nh) {
                const int p = 16*nh + r;
                bf16x8 Bf;
                if (kh < 2) {
                    Bf = *(const bf16x8*)((const char*)Xe + p*128 +
                          ((kh*64 + q*16) ^ ((p & 7) << 4)));
                } else {
                    const char* hb = (const char*)&Hs[cur][0] + p*256;
                    const int cbb = (kh - 2)*128 + q*32;
                    const int sw = (p & 15) << 4;
                    f32x4 f0 = *(const f32x4*)(hb + (cbb ^ sw));
                    f32x4 f1 = *(const f32x4*)(hb + ((cbb + 16) ^ sw));
                    Bf[0]=(__bf16)f0[0]; Bf[1]=(__bf16)f0[1]; Bf[2]=(__bf16)f0[2]; Bf[3]=(__bf16)f0[3];
                    Bf[4]=(__bf16)f1[0]; Bf[5]=(__bf16)f1[1]; Bf[6]=(__bf16)f1[2]; Bf[7]=(__bf16)f1[3];
                }
                acc[0][nh] = __builtin_amdgcn_mfma_f32_16x16x32_bf16(Af0, Bf, acc[0][nh], 0, 0, 0);
                acc[1][nh] = __builtin_amdgcn_mfma_f32_16x16x32_bf16(Af1, Bf, acc[1][nh], 0, 0, 0);
            }
        }
        f32x2 cpre[2];
#pragma unroll
        for (int nh = 0; nh < 2; ++nh) {
            const int p = 16*nh + r;
            cpre[nh] = *(const f32x2*)((const char*)&Cs[cur][0] + p*256 +
                        ((32*w + 8*q) ^ ((p & 15) << 4)));
        }

        // ---- phase B: LSTM elementwise (base-2) + score partials ----
        float Eev[2][2];
        float sp[2] = {0.f, 0.f};
#pragma unroll
        for (int nh = 0; nh < 2; ++nh) {
#pragma unroll
            for (int mh = 0; mh < 2; ++mh) {
                f32x4 g4 = acc[mh][nh];
                float si = rcp_(1.f + ex2(g4[0]));
                float sf = rcp_(1.f + ex2(g4[1]));
                float so = rcp_(1.f + ex2(g4[3]));
                float tt = ex2(-__builtin_fabsf(g4[2]));
                float tg = __builtin_copysignf((1.f - tt) * rcp_(1.f + tt), -g4[2]);
                float cn = fmaf(sf, cpre[nh][mh], si * tg);
                float t2 = ex2(-__builtin_fabsf(cn) * (2.f * L2E));
                float tc = __builtin_copysignf((1.f - t2) * rcp_(1.f + t2), cn);
                float h = so * tc;
                h = (16*nh + r == b - base) ? hsd[mh] : h;
                Eev[mh][nh] = h;
                sp[nh] = fmaf(qkr[mh], h, sp[nh]);
            }
        }
#pragma unroll
        for (int nh = 0; nh < 2; ++nh) {
            float v = sp[nh];
            v += __shfl_xor(v, 16, 64);
            v += __shfl_xor(v, 32, 64);
            if (q == 0) spart[w][16*nh + r] = v;
        }
        asm volatile("s_waitcnt lgkmcnt(0)" ::: "memory");
        __builtin_amdgcn_s_barrier();
        __builtin_amdgcn_sched_barrier(0);

        // ---- phase C: online softmax (dup across halves/waves) + ctx ----
        {
            const int c = l & 31;
            float s_p = spart[0][c];
#pragma unroll
            for (int i = 1; i < 8; ++i) s_p += spart[i][c];
            float tm = s_p;
#pragma unroll
            for (int off = 1; off < 32; off <<= 1) tm = fmaxf(tm, __shfl_xor(tm, off, 64));
            float m_new = fmaxf(m_run, tm);
            float corr = ex2(m_run - m_new);
            float wp = ex2(s_p - m_new);
            l_run = fmaf(l_run, corr, wp);
            m_run = m_new;
            float wn0 = __shfl(wp, r, 64);
            float wn1 = __shfl(wp, 16 + r, 64);
#pragma unroll
            for (int mh = 0; mh < 2; ++mh)
                ctxa[mh] = fmaf(wn1, Eev[mh][1], fmaf(wn0, Eev[mh][0], ctxa[mh] * corr));
        }
        // ---- phase D: embed next tile; issue next stage; counted-wait barrier ----
        if (t < NT - 1) {
            embedW((t+1)*TILE);
            stageT(hp_half + (size_t)(t+1)*TILE*EE, Hs[cur^1]);
            stageT(cp_half + (size_t)(t+1)*TILE*EE, Cs[cur^1]);
            asm volatile("s_waitcnt vmcnt(2) lgkmcnt(0)" ::: "memory");
        } else {
            asm volatile("s_waitcnt vmcnt(0) lgkmcnt(0)" ::: "memory");
        }
        __builtin_amdgcn_s_barrier();
        __builtin_amdgcn_sched_barrier(0);
    }

    // ---- epilogue: write partial (unnormalized ctx, m, l) ----
    float l_tot = l_run;
#pragma unroll
    for (int off = 1; off < 32; off <<= 1) l_tot += __shfl_xor(l_tot, off, 64);
    float* pp = g_part[bh];
#pragma unroll
    for (int mh = 0; mh < 2; ++mh) {
        float v = ctxa[mh];
        v += __shfl_xor(v, 1, 64);
        v += __shfl_xor(v, 2, 64);
        v += __shfl_xor(v, 4, 64);
        v += __shfl_xor(v, 8, 64);
        if (r == 0) pp[ebase0 + mh] = v;
    }
    if (tid == 0) { pp[64] = m_run; pp[65] = l_tot; }
}

// ---------------- merge: combine halves + fused output projection -----------
__global__ __launch_bounds__(64) void merge_kernel(float* __restrict__ out)
{
    __shared__ float ctxL[64];
    const int b = blockIdx.x, tid = threadIdx.x;
    const float* p0 = g_part[2*b];
    const float* p1 = g_part[2*b + 1];
    float m0 = p0[64], l0 = p0[65];
    float m1 = p1[64], l1 = p1[65];
    float M  = fmaxf(m0, m1);
    float f0 = ex2(m0 - M), f1 = ex2(m1 - M);
    float inv = rcp_(fmaf(l0, f0, l1 * f1));
    ctxL[tid] = (p0[tid]*f0 + p1[tid]*f1) * inv;
    __syncthreads();
    if (tid < OUTD) {
        float s = g_btot[tid];
        const float* wr2 = g_Wtot + tid*64;
        for (int k = 0; k < 64; ++k) s = fmaf(wr2[k], ctxL[k], s);
        out[b*OUTD + tid] = s;
    }
}

extern "C" void kernel_launch(void* const* d_in, const int* in_sizes, int n_in,
                              void* d_out, int out_size, void* d_ws, size_t ws_size,
                              hipStream_t stream) {
    const float* hidden = (const float*)d_in[0];
    const float* obs1   = (const float*)d_in[1];
    const float* obs2   = (const float*)d_in[2];
    const float* h0     = (const float*)d_in[3];
    const float* c0     = (const float*)d_in[4];
    const float* W_s    = (const float*)d_in[5];
    const float* b_s    = (const float*)d_in[6];
    const float* W_v    = (const float*)d_in[7];
    const float* b_v    = (const float*)d_in[8];
    const float* W_hs   = (const float*)d_in[9];
    const float* b_hs   = (const float*)d_in[10];
    const float* W_ih   = (const float*)d_in[11];
    const float* b_ih   = (const float*)d_in[12];
    const float* W_hh   = (const float*)d_in[13];
    const float* b_hh   = (const float*)d_in[14];
    const float* Wq     = (const float*)d_in[15];
    const float* Wk     = (const float*)d_in[16];
    const float* Wv     = (const float*)d_in[17];
    const float* W_in   = (const float*)d_in[18];
    const float* b_in   = (const float*)d_in[19];
    const float* W_out  = (const float*)d_in[20];
    const float* b_out  = (const float*)d_in[21];
    const float* W_o    = (const float*)d_in[22];
    const float* b_o    = (const float*)d_in[23];

    prepW<<<dim3(8), dim3(256), 0, stream>>>(
        W_ih, b_ih, W_hh, b_hh, Wq, Wk, Wv, W_in, W_hs, W_s, b_s, W_v, b_v);
    prepW2<<<dim3(2), dim3(256), 0, stream>>>(b_in, W_out, b_out, W_o, b_o);
    row_kernel<<<dim3(2*NN), dim3(512), 0, stream>>>(
        hidden, b_hs, obs1, obs2, h0, c0);
    merge_kernel<<<dim3(NN), dim3(64), 0, stream>>>((float*)d_out);
}